// Round 1
// 1083.460 us; speedup vs baseline: 1.2929x; 1.2929x over previous
//
#include <hip/hip_runtime.h>
#include <stdint.h>

#define MDIM 4096
#define NDIM 4096
#define KDIM 4096
#define BATCH 4

typedef __bf16 bf16x8 __attribute__((ext_vector_type(8)));
typedef float f32x4 __attribute__((ext_vector_type(4)));

typedef const __attribute__((address_space(1))) void gvoid;
typedef __attribute__((address_space(3))) void lvoid;

// shared block scale: 2^(floor(log2(amax)) - 2), bit-exact exponent extract.
__device__ __forceinline__ void quant_scales(float amax, float& scale, float& inv_scale) {
    int ex = (int)(__float_as_uint(amax) >> 23) - 127;   // floor(log2(amax)) for normal amax
    ex = ex < -120 ? -120 : (ex > 120 ? 120 : ex);       // amax==0 -> q==0 anyway
    scale     = __int_as_float((ex + 125) << 23);        // 2^(ex-2)
    inv_scale = __int_as_float((129 - ex) << 23);        // 2^(2-ex)
}

// E2M1 fake-quant of one element; returns bf16 bits (exact: <=2 significant bits)
__device__ __forceinline__ ushort quant_one(float x, float scale, float inv_scale) {
    float a = fminf(fabsf(x) * inv_scale, 6.0f);
    float rstep = (a < 2.0f) ? 2.0f : ((a < 4.0f) ? 1.0f : 0.5f);
    float step  = (a < 2.0f) ? 0.5f : ((a < 4.0f) ? 1.0f : 2.0f);
    float q = rintf(a * rstep) * step;                   // RNE == jnp.round
    float v = copysignf(q * scale, x);
    return (ushort)(__float_as_uint(v) >> 16);           // exact fp32->bf16
}

// A: (b, m, k) fp32, quantize along k (contiguous). 8 elem/thread; 4 threads = one 32-block.
__global__ __launch_bounds__(256) void quant_a_kernel(const float* __restrict__ A,
                                                      ushort* __restrict__ Aq) {
    const long long base = ((long long)blockIdx.x * 256 + threadIdx.x) * 8;
    const float4 v0 = *(const float4*)(A + base);
    const float4 v1 = *(const float4*)(A + base + 4);
    float x[8] = {v0.x, v0.y, v0.z, v0.w, v1.x, v1.y, v1.z, v1.w};
    float amax = 0.0f;
#pragma unroll
    for (int i = 0; i < 8; ++i) amax = fmaxf(amax, fabsf(x[i]));
    amax = fmaxf(amax, __shfl_xor(amax, 1));
    amax = fmaxf(amax, __shfl_xor(amax, 2));
    float scale, inv_scale;
    quant_scales(amax, scale, inv_scale);
    ushort o[8];
#pragma unroll
    for (int i = 0; i < 8; ++i) o[i] = quant_one(x[i], scale, inv_scale);
    uint4 pack;
    pack.x = (uint)o[0] | ((uint)o[1] << 16);
    pack.y = (uint)o[2] | ((uint)o[3] << 16);
    pack.z = (uint)o[4] | ((uint)o[5] << 16);
    pack.w = (uint)o[6] | ((uint)o[7] << 16);
    *(uint4*)(Aq + base) = pack;
}

// B: (b, k, n) fp32, quantize along k (stride N). Output written TRANSPOSED as Bqt (b, n, k).
__global__ __launch_bounds__(256) void quant_b_kernel(const float* __restrict__ B,
                                                      ushort* __restrict__ Bqt) {
    __shared__ ushort S[64][132];   // [n][k], +4 pad: 66-dword row stride -> 2-way (free)
    const int b    = blockIdx.z;
    const int n0   = blockIdx.x * 64;
    const int k0   = blockIdx.y * 128;
    const int lane = threadIdx.x & 63;   // n within tile
    const int w    = threadIdx.x >> 6;   // which 32-k-block of the 128
    const float* src = B + ((long long)b * KDIM + (k0 + w * 32)) * NDIM + (n0 + lane);
    float x[32];
    float amax = 0.0f;
#pragma unroll
    for (int i = 0; i < 32; ++i) {
        x[i] = src[(size_t)i * NDIM];                    // coalesced 256B across wave
        amax = fmaxf(amax, fabsf(x[i]));
    }
    float scale, inv_scale;
    quant_scales(amax, scale, inv_scale);
#pragma unroll
    for (int i = 0; i < 32; ++i) S[lane][w * 32 + i] = quant_one(x[i], scale, inv_scale);
    __syncthreads();
    ushort* dstbase = Bqt + ((long long)b * NDIM + n0) * KDIM + k0;
#pragma unroll
    for (int it = 0; it < 4; ++it) {
        int G = it * 256 + threadIdx.x;   // 1024 granules of 16B: 64 rows x 16
        int row = G >> 4;
        int c = (G & 15) * 8;
        uint2 lo = *(const uint2*)&S[row][c];
        uint2 hi = *(const uint2*)&S[row][c + 4];
        uint4 out; out.x = lo.x; out.y = lo.y; out.z = hi.x; out.w = hi.y;
        *(uint4*)(dstbase + (size_t)row * KDIM + c) = out;   // 256B segments per row
    }
}

// ---------------------------------------------------------------------------
// GEMM: C[b] = Aq[b] (M,K) @ Bqt[b]^T  (Bqt is (N,K)).
// 256x256 tile, BK=64, 8 waves (2M x 4N), 8-phase-style schedule (m201 template):
//   per K-tile: 4 phases of {ds_read subtile | stage 1 half-tile | s_barrier |
//   lgkmcnt(0) | setprio(1) 16xMFMA setprio(0) | s_barrier}.
//   One counted vmcnt(6) per K-tile (phase 4), never 0 in the main loop.
// LDS 128 KiB = 2 parity x {A,B} x 2 K-half x 16 KiB half-tiles.
// Pipeline bookkeeping (per-wave, 2 loads per half-tile):
//   prologue: tile0 (4 halves) + tile1 {Bk0,Ak0,Bk1}; vmcnt(6) lands tile0.
//   tile T phases stage: ph1 A-k1(T+1) | ph2 B-k0(T+2) | ph3 A-k0(T+2) | ph4 B-k1(T+2).
//   At ph4's vmcnt(6): 14 outstanding, oldest 8 = ALL of tile T+1 -> landed;
//   3 halves of T+2 stay in flight, each targeting a slot whose last reader
//   finished >=2 barriers before the load was issued (race-free).
// T2 swizzle: read slot s' = (l>>4)^(l&3)^((l>>2)&3); staging pre-swizzles the
// GLOBAL source k-slot with the same involution so the linear global_load_lds
// dest matches (both-sides-or-neither, rule #21). 2 lanes/bank = free.
// ---------------------------------------------------------------------------
#define BM 256
#define BN 256
#define BK 64
#define NT (KDIM / BK)   // 64 K-tiles

// LDS region base (ushort units): parity p, op o (0=A,1=B), k-half h. 8192 ushorts each.
#define REG(p, o, h) ((((((p) << 1) | (o)) << 1) | (h)) * 8192)

__global__ __launch_bounds__(512, 2) void gemm_kernel(const ushort* __restrict__ Aq,
                                                      const ushort* __restrict__ Bqt,
                                                      float* __restrict__ C) {
    __shared__ __align__(16) ushort LDS[65536];   // 128 KiB
    const int t = threadIdx.x;
    const int l = t & 63;
    const int w = t >> 6;
    const int wm = w >> 2;      // 0..1 -> M offset wm*128
    const int wn = w & 3;       // 0..3 -> N offset wn*64
    const int m0 = blockIdx.y * BM, n0 = blockIdx.x * BN;
    const int bb = blockIdx.z;

    const ushort* Ab = Aq  + (size_t)bb * MDIM * KDIM + (size_t)m0 * KDIM;
    const ushort* Bb = Bqt + (size_t)bb * NDIM * KDIM + (size_t)n0 * KDIM;

    // staging: granule G = w*64 + c*512 + l (16B each), LDS dest byte = G*16 (linear).
    // global src row r = G>>2; k-slot s = (G&3)^((G>>2)&3)^((G>>4)&3) -> per-thread sw.
    const int sw = (l & 3) ^ ((l >> 2) & 3) ^ (l >> 4);
    const int r0 = w * 16 + (l >> 2);                    // rows 0..127 (call 0)
    const ushort* aS0 = Ab + (size_t)r0 * KDIM + sw * 8;
    const ushort* aS1 = aS0 + (size_t)128 * KDIM;        // rows 128..255 (call 1)
    const ushort* bS0 = Bb + (size_t)r0 * KDIM + sw * 8;
    const ushort* bS1 = bS0 + (size_t)128 * KDIM;
    const int d0 = (w * 64 + l) * 8;                     // LDS dest, ushort units
    const int d1 = d0 + 4096;

#define GLL(src, dofs) \
    __builtin_amdgcn_global_load_lds((gvoid*)(src), (lvoid*)(LDS + (dofs)), 16, 0, 0)
#define STAGE_A(p, h, kofs) do { GLL(aS0 + (kofs), REG(p, 0, h) + d0); \
                                 GLL(aS1 + (kofs), REG(p, 0, h) + d1); } while (0)
#define STAGE_B(p, h, kofs) do { GLL(bS0 + (kofs), REG(p, 1, h) + d0); \
                                 GLL(bS1 + (kofs), REG(p, 1, h) + d1); } while (0)

    // fragment read offsets (ushort units within a 16 KiB region), swizzled slot sw
    const int aro = wm * 4096 + (l & 15) * 32 + sw * 8;  // + i*512 per m-frag (i=0..7)
    const int bro = wn * 2048 + (l & 15) * 32 + sw * 8;  // + j*512 per n-frag (j=0..3)

    f32x4 zero = {0.f, 0.f, 0.f, 0.f};
    f32x4 acc[8][4];
#pragma unroll
    for (int i = 0; i < 8; ++i)
#pragma unroll
        for (int j = 0; j < 4; ++j) acc[i][j] = zero;

    // ---- prologue: tile0 fully + 3 halves of tile1; land tile0, keep 3 in flight ----
    STAGE_A(0, 0, 0);  STAGE_B(0, 0, 0);
    STAGE_A(0, 1, 32); STAGE_B(0, 1, 32);
    STAGE_B(1, 0, 64); STAGE_A(1, 0, 64); STAGE_B(1, 1, 96);
    asm volatile("s_waitcnt vmcnt(6)" ::: "memory");
    __builtin_amdgcn_s_barrier();

    bf16x8 af[4], bf[4];
    for (int T = 0; T < NT - 1; ++T) {
        const int p   = T & 1;
        const int kA1 = (T + 1) * BK + 32;   // A-k1 of next tile
        const int kN  = (T + 2) * BK;        // tile T+2 base (guarded)
        const ushort* A0 = LDS + REG(p, 0, 0) + aro;
        const ushort* B0 = LDS + REG(p, 1, 0) + bro;
        const ushort* A1 = LDS + REG(p, 0, 1) + aro;
        const ushort* B1 = LDS + REG(p, 1, 1) + bro;

        // ---- phase 1: k-half 0, m-frags 0..3 ----
#pragma unroll
        for (int i = 0; i < 4; ++i) af[i] = *(const bf16x8*)(A0 + i * 512);
#pragma unroll
        for (int j = 0; j < 4; ++j) bf[j] = *(const bf16x8*)(B0 + j * 512);
        STAGE_A(p ^ 1, 1, kA1);
        __builtin_amdgcn_s_barrier();
        asm volatile("s_waitcnt lgkmcnt(0)" ::: "memory");
        __builtin_amdgcn_s_setprio(1);
#pragma unroll
        for (int i = 0; i < 4; ++i)
#pragma unroll
            for (int j = 0; j < 4; ++j)
                acc[i][j] = __builtin_amdgcn_mfma_f32_16x16x32_bf16(af[i], bf[j], acc[i][j], 0, 0, 0);
        __builtin_amdgcn_s_setprio(0);
        __builtin_amdgcn_s_barrier();

        // ---- phase 2: k-half 0, m-frags 4..7 (B reused in regs) ----
#pragma unroll
        for (int i = 0; i < 4; ++i) af[i] = *(const bf16x8*)(A0 + (i + 4) * 512);
        if (T < NT - 2) STAGE_B(p, 0, kN);
        __builtin_amdgcn_s_barrier();
        asm volatile("s_waitcnt lgkmcnt(0)" ::: "memory");
        __builtin_amdgcn_s_setprio(1);
#pragma unroll
        for (int i = 0; i < 4; ++i)
#pragma unroll
            for (int j = 0; j < 4; ++j)
                acc[i + 4][j] = __builtin_amdgcn_mfma_f32_16x16x32_bf16(af[i], bf[j], acc[i + 4][j], 0, 0, 0);
        __builtin_amdgcn_s_setprio(0);
        __builtin_amdgcn_s_barrier();

        // ---- phase 3: k-half 1, m-frags 0..3 ----
#pragma unroll
        for (int i = 0; i < 4; ++i) af[i] = *(const bf16x8*)(A1 + i * 512);
#pragma unroll
        for (int j = 0; j < 4; ++j) bf[j] = *(const bf16x8*)(B1 + j * 512);
        if (T < NT - 2) STAGE_A(p, 0, kN);
        __builtin_amdgcn_s_barrier();
        asm volatile("s_waitcnt lgkmcnt(0)" ::: "memory");
        __builtin_amdgcn_s_setprio(1);
#pragma unroll
        for (int i = 0; i < 4; ++i)
#pragma unroll
            for (int j = 0; j < 4; ++j)
                acc[i][j] = __builtin_amdgcn_mfma_f32_16x16x32_bf16(af[i], bf[j], acc[i][j], 0, 0, 0);
        __builtin_amdgcn_s_setprio(0);
        __builtin_amdgcn_s_barrier();

        // ---- phase 4: k-half 1, m-frags 4..7; counted vmcnt closes the K-tile ----
#pragma unroll
        for (int i = 0; i < 4; ++i) af[i] = *(const bf16x8*)(A1 + (i + 4) * 512);
        if (T < NT - 2) {
            STAGE_B(p, 1, kN + 32);
            asm volatile("s_waitcnt vmcnt(6)" ::: "memory");   // tile T+1 fully landed
        } else {
            asm volatile("s_waitcnt vmcnt(0)" ::: "memory");   // drain for the tail tile
        }
        __builtin_amdgcn_s_barrier();
        asm volatile("s_waitcnt lgkmcnt(0)" ::: "memory");
        __builtin_amdgcn_s_setprio(1);
#pragma unroll
        for (int i = 0; i < 4; ++i)
#pragma unroll
            for (int j = 0; j < 4; ++j)
                acc[i + 4][j] = __builtin_amdgcn_mfma_f32_16x16x32_bf16(af[i], bf[j], acc[i + 4][j], 0, 0, 0);
        __builtin_amdgcn_s_setprio(0);
        __builtin_amdgcn_s_barrier();
    }

    // ---- tail tile (T = NT-1): all data resident, no staging, no barriers needed ----
    {
        const int p = (NT - 1) & 1;
        const ushort* A0 = LDS + REG(p, 0, 0) + aro;
        const ushort* B0 = LDS + REG(p, 1, 0) + bro;
        const ushort* A1 = LDS + REG(p, 0, 1) + aro;
        const ushort* B1 = LDS + REG(p, 1, 1) + bro;
#pragma unroll
        for (int i = 0; i < 4; ++i) af[i] = *(const bf16x8*)(A0 + i * 512);
#pragma unroll
        for (int j = 0; j < 4; ++j) bf[j] = *(const bf16x8*)(B0 + j * 512);
#pragma unroll
        for (int i = 0; i < 4; ++i)
#pragma unroll
            for (int j = 0; j < 4; ++j)
                acc[i][j] = __builtin_amdgcn_mfma_f32_16x16x32_bf16(af[i], bf[j], acc[i][j], 0, 0, 0);
#pragma unroll
        for (int i = 0; i < 4; ++i) af[i] = *(const bf16x8*)(A0 + (i + 4) * 512);
#pragma unroll
        for (int i = 0; i < 4; ++i)
#pragma unroll
            for (int j = 0; j < 4; ++j)
                acc[i + 4][j] = __builtin_amdgcn_mfma_f32_16x16x32_bf16(af[i], bf[j], acc[i + 4][j], 0, 0, 0);
#pragma unroll
        for (int i = 0; i < 4; ++i) af[i] = *(const bf16x8*)(A1 + i * 512);
#pragma unroll
        for (int j = 0; j < 4; ++j) bf[j] = *(const bf16x8*)(B1 + j * 512);
#pragma unroll
        for (int i = 0; i < 4; ++i)
#pragma unroll
            for (int j = 0; j < 4; ++j)
                acc[i][j] = __builtin_amdgcn_mfma_f32_16x16x32_bf16(af[i], bf[j], acc[i][j], 0, 0, 0);
#pragma unroll
        for (int i = 0; i < 4; ++i) af[i] = *(const bf16x8*)(A1 + (i + 4) * 512);
#pragma unroll
        for (int i = 0; i < 4; ++i)
#pragma unroll
            for (int j = 0; j < 4; ++j)
                acc[i + 4][j] = __builtin_amdgcn_mfma_f32_16x16x32_bf16(af[i], bf[j], acc[i + 4][j], 0, 0, 0);
    }

    // ---- epilogue: C/D layout col = lane&15, row = (lane>>4)*4 + reg ----
    float* Cb = C + ((size_t)bb * MDIM + m0 + wm * 128) * NDIM + n0 + wn * 64;
#pragma unroll
    for (int i = 0; i < 8; ++i) {
        const int row = i * 16 + ((l >> 4) * 4);
#pragma unroll
        for (int j = 0; j < 4; ++j) {
            const int col = j * 16 + (l & 15);
#pragma unroll
            for (int r = 0; r < 4; ++r)
                Cb[(size_t)(row + r) * NDIM + col] = acc[i][j][r];
        }
    }
}

extern "C" void kernel_launch(void* const* d_in, const int* in_sizes, int n_in,
                              void* d_out, int out_size, void* d_ws, size_t ws_size,
                              hipStream_t stream) {
    (void)in_sizes; (void)n_in; (void)out_size; (void)ws_size;
    const float* A = (const float*)d_in[0];
    const float* B = (const float*)d_in[1];
    float* C = (float*)d_out;
    ushort* Aq  = (ushort*)d_ws;                               // 128 MiB
    ushort* Bqt = Aq + (size_t)BATCH * MDIM * KDIM;            // 128 MiB

    quant_a_kernel<<<(BATCH * (size_t)MDIM * KDIM) / 2048, 256, 0, stream>>>(A, Aq);
    dim3 gb(NDIM / 64, KDIM / 128, BATCH);
    quant_b_kernel<<<gb, 256, 0, stream>>>(B, Bqt);
    dim3 gg(NDIM / BN, MDIM / BM, BATCH);
    gemm_kernel<<<gg, 512, 0, stream>>>(Aq, Bqt, C);
}